// Round 11
// baseline (1278.035 us; speedup 1.0000x reference)
//
#include <hip/hip_runtime.h>

#define K 8192
#define NROWS 8192
#define NSTEPS 100
#define CHUNK 20
#define NPASS 5
#define QEPS 1.1920928955078125e-07f

// Wave-uniform value -> SGPR (int-bitcast form compiles on all ROCm).
__device__ __forceinline__ float rdfirst(float v) {
    return __int_as_float(__builtin_amdgcn_readfirstlane(__float_as_int(v)));
}

// Step-chunked structure: 5 passes x 20 steps. Each pass streams the row
// through ONE float4 (re-read from L2/L3, ~1.3GB total) and keeps 20
// accumulators + 40 SGPR scales. Natural VGPR pressure ~45 < 64, so the
// occupancy-driven rematerializer has no incentive to sink loads (rounds
// 1-10 showed it re-sinks any 32-value register-resident row, costing
// 25.6TB of L2 re-reads = ~755us at the L2 ceiling).
__global__ __launch_bounds__(256) void mse_observer_kernel(
    const float* __restrict__ x, float* __restrict__ out)
{
    const int row  = blockIdx.x;
    const int tid  = threadIdx.x;
    const int lane = tid & 63;
    const int wave = tid >> 6;

    const float4* __restrict__ xr =
        reinterpret_cast<const float4*>(x + (size_t)row * K);

    // ---- Phase 1: row min/max (streaming; values not retained) ----
    float vmin =  3.4e38f, vmax = -3.4e38f;
    #pragma unroll
    for (int j = 0; j < 8; ++j) {
        float4 v = xr[tid + j * 256];
        vmin = fminf(vmin, fminf(fminf(v.x, v.y), fminf(v.z, v.w)));
        vmax = fmaxf(vmax, fmaxf(fmaxf(v.x, v.y), fmaxf(v.z, v.w)));
    }
    #pragma unroll
    for (int off = 32; off >= 1; off >>= 1) {
        vmin = fminf(vmin, __shfl_xor(vmin, off));
        vmax = fmaxf(vmax, __shfl_xor(vmax, off));
    }

    __shared__ float  smin[4], smax[4];
    __shared__ float2 sitab[NSTEPS];      // (s, 1/s) per step
    __shared__ float  partial[NSTEPS * 4];
    __shared__ float  sloss[NSTEPS];

    if (lane == 0) { smin[wave] = vmin; smax[wave] = vmax; }
    __syncthreads();

    const float rmin  = fminf(fminf(smin[0], smin[1]), fminf(smin[2], smin[3]));
    const float rmax  = fmaxf(fmaxf(smax[0], smax[1]), fmaxf(smax[2], smax[3]));
    const float range = fmaxf(fabsf(rmin), rmax);
    const float rstep = range / (float)NSTEPS;   // matches range_val / STEPS

    if (tid < NSTEPS) {
        const float thres = rstep * (float)(tid + 1);
        const float s     = fmaxf(thres / 127.5f, QEPS);
        sitab[tid] = make_float2(s, 1.0f / s);
    }
    __syncthreads();

    // ---- Phase 2: chunked step sweep ----
    #pragma unroll 1
    for (int p = 0; p < NPASS; ++p) {
        // Chunk scales -> SGPRs (wave-uniform; VALU reads 1 SGPR op free).
        float ss[CHUNK], si[CHUNK];
        #pragma unroll
        for (int st = 0; st < CHUNK; ++st) {
            float2 sv = sitab[p * CHUNK + st];
            ss[st] = rdfirst(sv.x);
            si[st] = rdfirst(sv.y);
        }
        float acc[CHUNK];
        #pragma unroll
        for (int st = 0; st < CHUNK; ++st) acc[st] = 0.0f;

        float4 cur = xr[tid];
        #pragma unroll 1   // rolled: hot body ~3KB, fits I$; 20 indep FMA chains
        for (int j = 0; j < 8; ++j) {
            const int jn = (j + 1) & 7;
            float4 nxt = xr[tid + jn * 256];   // prefetch (j=7 dummy, unused)
            #pragma unroll
            for (int st = 0; st < CHUNK; ++st) {
                const float s_ = ss[st], i_ = si[st];
                float q, d;
                q = __builtin_amdgcn_fmed3f(__builtin_rintf(cur.x * i_), -128.f, 127.f);
                d = __builtin_fmaf(q, s_, -cur.x); acc[st] = __builtin_fmaf(d, d, acc[st]);
                q = __builtin_amdgcn_fmed3f(__builtin_rintf(cur.y * i_), -128.f, 127.f);
                d = __builtin_fmaf(q, s_, -cur.y); acc[st] = __builtin_fmaf(d, d, acc[st]);
                q = __builtin_amdgcn_fmed3f(__builtin_rintf(cur.z * i_), -128.f, 127.f);
                d = __builtin_fmaf(q, s_, -cur.z); acc[st] = __builtin_fmaf(d, d, acc[st]);
                q = __builtin_amdgcn_fmed3f(__builtin_rintf(cur.w * i_), -128.f, 127.f);
                d = __builtin_fmaf(q, s_, -cur.w); acc[st] = __builtin_fmaf(d, d, acc[st]);
            }
            cur = nxt;
        }

        // Wave-reduce each accumulator; lane0 writes its (step,wave) slot.
        #pragma unroll
        for (int st = 0; st < CHUNK; ++st) {
            float a = acc[st];
            #pragma unroll
            for (int off = 32; off >= 1; off >>= 1) a += __shfl_xor(a, off);
            if (lane == 0) partial[(p * CHUNK + st) * 4 + wave] = a;
        }
    }
    __syncthreads();

    // Combine wave partials (sum over row; mean = sum * 2^-13 exact, argmin same)
    if (tid < NSTEPS) {
        sloss[tid] = (partial[tid * 4 + 0] + partial[tid * 4 + 1]) +
                     (partial[tid * 4 + 2] + partial[tid * 4 + 3]);
    }
    __syncthreads();

    if (tid == 0) {
        float opt = 3.4e38f;
        int best = 0;
        #pragma unroll 1
        for (int i = 0; i < NSTEPS; ++i) {
            float l = sloss[i];
            if (l < opt) { opt = l; best = i; }   // strict <: earliest min
        }
        const float tbest = rstep * (float)(best + 1);
        out[row]         = -tbest;   // min_val
        out[NROWS + row] =  tbest;   // max_val
    }
}

extern "C" void kernel_launch(void* const* d_in, const int* in_sizes, int n_in,
                              void* d_out, int out_size, void* d_ws, size_t ws_size,
                              hipStream_t stream) {
    const float* x = (const float*)d_in[0];
    float* out = (float*)d_out;
    mse_observer_kernel<<<NROWS, 256, 0, stream>>>(x, out);
}